// Round 12
// baseline (147.920 us; speedup 1.0000x reference)
//
#include <hip/hip_runtime.h>
#include <hip/hip_bf16.h>

// RandomProjectionQuantizer — MFMA screen, coalesced/conflict-free project (R12).
//  x:(16,2048,320) f32, mask:(16,2048) i32 (exactly 16384 ones),
//  W:(16,320) f32, codebook:(8192,16) f32 -> scalar int32 label
//
//  D-split reindexed (j*32 + ch*4):
//   - x reads: 8 ch-lanes/row cover contiguous 128B per j  -> coalesced
//   - LDS W reads: bank = ch*4+k -> all 32 banks, ZERO conflicts, no transpose
//   - x prefetched to 10 float4 regs -> 10-deep MLP
//  cproj recomputes the identical new-order chain (bit-equal t for rescore).
//  phase1/gate/rescore/emit: R11-verbatim (proven).

#define NMASK   16384
#define NROWS   32768
#define D       320
#define CDIM    16
#define NCODES  8192
#define EPS_C   0.0117f      // 1.5 * 2^-7  (bf16 RNE dot-error coefficient)
#define EPS_ABS 0.02f

typedef __attribute__((ext_vector_type(8))) short short8;
typedef __attribute__((ext_vector_type(4))) float f32x4;

__device__ inline unsigned int encf(float f) {
  unsigned int u = __float_as_uint(f);
  return (u & 0x80000000u) ? ~u : (u | 0x80000000u);
}
__device__ inline float decf(unsigned int u) {
  unsigned int b = (u & 0x80000000u) ? (u & 0x7fffffffu) : ~u;
  return __uint_as_float(b);
}
__device__ inline unsigned short f2bf(float f) {   // RNE f32->bf16
  unsigned int u = __float_as_uint(f);
  unsigned int r = u + 0x7fffu + ((u >> 16) & 1u);
  return (unsigned short)(r >> 16);
}
__device__ inline float bf2f(unsigned short h) {
  return __uint_as_float(((unsigned int)h) << 16);
}

// projection, NEW chunking: lane ch covers d in { j*32 + ch*4 .. +4 : j=0..9 }.
// butterfly combine (xor 1,2,4). Used bit-identically by project (LDS W) and
// cproj (global W) — same values, same FMA order.
__device__ inline void proj_row8(const float* __restrict__ x,
                                 const float* __restrict__ W,
                                 int row, int ch, float pd[16]) {
#pragma unroll
  for (int c = 0; c < 16; ++c) pd[c] = 0.f;
  const float* xr = x + (size_t)row * D + ch * 4;
  float4 xv[10];
#pragma unroll
  for (int j = 0; j < 10; ++j) xv[j] = *(const float4*)(xr + j * 32);
#pragma unroll
  for (int j = 0; j < 10; ++j) {
#pragma unroll
    for (int c = 0; c < 16; ++c) {
      const float4 wv = *(const float4*)(W + c * D + j * 32 + ch * 4);
      float acc = fmaf(xv[j].x, wv.x, pd[c]);
      acc = fmaf(xv[j].y, wv.y, acc);
      acc = fmaf(xv[j].z, wv.z, acc);
      pd[c] = fmaf(xv[j].w, wv.w, acc);
    }
  }
#pragma unroll
  for (int c = 0; c < 16; ++c) {
    pd[c] += __shfl_xor(pd[c], 1);
    pd[c] += __shfl_xor(pd[c], 2);
    pd[c] += __shfl_xor(pd[c], 4);
  }
}

// ---------------- Kernel 1: project (1024 blocks x 256) ----------------------
__global__ __launch_bounds__(256) void project_kernel(
    const float* __restrict__ x, const int* __restrict__ mask,
    const float* __restrict__ W, const float* __restrict__ cbk,
    float* __restrict__ c2, unsigned short* __restrict__ cbf32,
    unsigned short* __restrict__ tbf32, float* __restrict__ t2arr,
    int* __restrict__ origrow, unsigned int* __restrict__ c2max_u,
    unsigned int* __restrict__ slotctr) {
  __shared__ float Wl[CDIM * D];                    // 20 KiB, natural layout
  __shared__ unsigned long long mb;
  int tid = threadIdx.x, bid = (int)blockIdx.x;
  int chunk = bid >> 1, half = bid & 1;
  for (int i = tid; i < (CDIM * D) / 4; i += 256)
    ((float4*)Wl)[i] = ((const float4*)W)[i];
  if (tid < 64) {
    int m = mask[chunk * 64 + tid];
    unsigned long long bal = __ballot(m != 0);
    if (tid == 0) mb = bal;
  }
  __syncthreads();

  if (bid < 512 && tid < 16) {                      // fused codes job (R5 fold)
    int k = bid * 16 + tid;
    const float4* p = (const float4*)(cbk + (long)k * CDIM);
    float s = 0.f; unsigned short nb[16];
#pragma unroll
    for (int q = 0; q < 4; ++q) {
      float4 v = p[q];
      s = fmaf(v.x, v.x, s); s = fmaf(v.y, v.y, s);
      s = fmaf(v.z, v.z, s); s = fmaf(v.w, v.w, s);
      nb[q*4+0] = f2bf(-2.0f * v.x); nb[q*4+1] = f2bf(-2.0f * v.y);
      nb[q*4+2] = f2bf(-2.0f * v.z); nb[q*4+3] = f2bf(-2.0f * v.w);
    }
    c2[k] = s;
    atomicMax(c2max_u, __float_as_uint(s));         // s >= 0: bits monotone
    unsigned short g1 = f2bf(s);
    unsigned short g2 = f2bf(s - bf2f(g1));
    uint4 pk0, pk1, pk2, pk3;
    pk0.x = (unsigned int)nb[0]  | ((unsigned int)nb[1]  << 16);
    pk0.y = (unsigned int)nb[2]  | ((unsigned int)nb[3]  << 16);
    pk0.z = (unsigned int)nb[4]  | ((unsigned int)nb[5]  << 16);
    pk0.w = (unsigned int)nb[6]  | ((unsigned int)nb[7]  << 16);
    pk1.x = (unsigned int)nb[8]  | ((unsigned int)nb[9]  << 16);
    pk1.y = (unsigned int)nb[10] | ((unsigned int)nb[11] << 16);
    pk1.z = (unsigned int)nb[12] | ((unsigned int)nb[13] << 16);
    pk1.w = (unsigned int)nb[14] | ((unsigned int)nb[15] << 16);
    pk2.x = (unsigned int)g1 | ((unsigned int)g2 << 16); // dims 16,17: g1,g2
    pk2.y = 0x3F803F80u;                                 // dims 18,19: 1,1
    pk2.z = 0u; pk2.w = 0u;
    pk3.x = 0u; pk3.y = 0u; pk3.z = 0u; pk3.w = 0u;
    uint4* dst = (uint4*)(cbf32 + (long)k * 32);
    dst[0] = pk0; dst[1] = pk1; dst[2] = pk2; dst[3] = pk3;
  }

  unsigned long long B0 = mb;
  int r = tid >> 3, ch = tid & 7, lane = tid & 63;
  int p = half * 32 + r;                            // bit position in chunk
  int row = chunk * 64 + p;
  int m = (int)((B0 >> p) & 1ull);

  // orderless slot assignment: one atomicAdd per wave (R11-proven)
  unsigned long long wbal = __ballot(m && ch == 0);
  unsigned int base = 0u;
  if (wbal) {
    int leader = (int)__ffsll((unsigned long long)wbal) - 1;
    if (lane == leader) base = atomicAdd(slotctr, (unsigned int)__popcll(wbal));
    base = (unsigned int)__shfl((int)base, leader);
  }
  if (!m) return;

  // projection from LDS-W: x coalesced (contig 128B per row per j),
  // LDS bank = ch*4+k -> conflict-free. Same chain as proj_row8.
  const float* xr = x + (size_t)row * D + ch * 4;
  float4 xv[10];
#pragma unroll
  for (int j = 0; j < 10; ++j) xv[j] = *(const float4*)(xr + j * 32);
  float pd[16];
#pragma unroll
  for (int c = 0; c < 16; ++c) pd[c] = 0.f;
#pragma unroll
  for (int j = 0; j < 10; ++j) {
#pragma unroll
    for (int c = 0; c < 16; ++c) {
      const float4 wv = *(const float4*)&Wl[c * D + j * 32 + ch * 4];
      float acc = fmaf(xv[j].x, wv.x, pd[c]);
      acc = fmaf(xv[j].y, wv.y, acc);
      acc = fmaf(xv[j].z, wv.z, acc);
      pd[c] = fmaf(xv[j].w, wv.w, acc);
    }
  }
#pragma unroll
  for (int c = 0; c < 16; ++c) {
    pd[c] += __shfl_xor(pd[c], 1);
    pd[c] += __shfl_xor(pd[c], 2);
    pd[c] += __shfl_xor(pd[c], 4);
  }

  if (ch == 0) {
    int slot = (int)base + __popcll(wbal & ((1ull << lane) - 1ull));
    float t2 = 0.f;
#pragma unroll
    for (int c = 0; c < 16; ++c) t2 = fmaf(pd[c], pd[c], t2);
    t2arr[slot] = t2;
    origrow[slot] = row;
    unsigned short tb[16];
#pragma unroll
    for (int c = 0; c < 16; ++c) tb[c] = f2bf(pd[c]);
    unsigned short h1 = f2bf(t2);
    unsigned short h2 = f2bf(t2 - bf2f(h1));
    uint4 pk0, pk1, pk2, pk3;
    pk0.x = (unsigned int)tb[0]  | ((unsigned int)tb[1]  << 16);
    pk0.y = (unsigned int)tb[2]  | ((unsigned int)tb[3]  << 16);
    pk0.z = (unsigned int)tb[4]  | ((unsigned int)tb[5]  << 16);
    pk0.w = (unsigned int)tb[6]  | ((unsigned int)tb[7]  << 16);
    pk1.x = (unsigned int)tb[8]  | ((unsigned int)tb[9]  << 16);
    pk1.y = (unsigned int)tb[10] | ((unsigned int)tb[11] << 16);
    pk1.z = (unsigned int)tb[12] | ((unsigned int)tb[13] << 16);
    pk1.w = (unsigned int)tb[14] | ((unsigned int)tb[15] << 16);
    pk2.x = 0x3F803F80u;                                 // dims 16,17: 1,1
    pk2.y = (unsigned int)h1 | ((unsigned int)h2 << 16); // dims 18,19: h1,h2
    pk2.z = 0u; pk2.w = 0u;
    pk3.x = 0u; pk3.y = 0u; pk3.z = 0u; pk3.w = 0u;
    uint4* dst = (uint4*)(tbf32 + (long)slot * 32);
    dst[0] = pk0; dst[1] = pk1; dst[2] = pk2; dst[3] = pk3;
  }
}

// ---------------- Kernel 2: calibrated per-row MFMA screening (verbatim) -----
__global__ __launch_bounds__(256) void phase1_kernel(
    const unsigned short* __restrict__ tbf32,
    const unsigned short* __restrict__ cbf32,
    unsigned int* __restrict__ rowmin_u) {
  __shared__ unsigned int rml[4 * 33];
  int tid = threadIdx.x;
  int w = tid >> 6, l = tid & 63, lr = l & 15, g = l >> 4;
  int strip = (int)blockIdx.x >> 2;                 // 0..511
  int seg   = ((int)blockIdx.x & 3) * 4 + w;        // 0..15
  int row0 = strip * 32;

  for (int i = tid; i < 4 * 33; i += 256) rml[i] = 0xFFFFFFFFu;
  __syncthreads();

  const f32x4 zero = {0.f, 0.f, 0.f, 0.f};
  short8 calA = {0,0,0,0,0,0,0,0}, calB = {0,0,0,0,0,0,0,0};
  if (g == 0) {
    calA[0] = (short)f2bf((float)(lr + 1));
    calB[0] = (short)0x3F80;                        // bf16 1.0
  }
  f32x4 cal = __builtin_amdgcn_mfma_f32_16x16x32_bf16(calA, calB, zero, 0, 0, 0);
  int rid[4];
#pragma unroll
  for (int j = 0; j < 4; ++j) {
    int v = (int)(cal[j] + 0.5f) - 1;
    rid[j] = v < 0 ? 0 : (v > 15 ? 15 : v);
  }

  const short8 a0 = *(const short8*)(tbf32 + (long)(row0 + lr) * 32 + g * 8);
  const short8 a1 = *(const short8*)(tbf32 + (long)(row0 + 16 + lr) * 32 + g * 8);
  f32x4 rmin0 = {3.4e38f, 3.4e38f, 3.4e38f, 3.4e38f};
  f32x4 rmin1 = rmin0;
  int code0 = seg * 512;
#pragma unroll 2
  for (int t = 0; t < 32; ++t) {
    int code = code0 + t * 16 + lr;
    short8 b = *(const short8*)(cbf32 + (long)code * 32 + g * 8);
    f32x4 d0 = __builtin_amdgcn_mfma_f32_16x16x32_bf16(a0, b, zero, 0, 0, 0);
    f32x4 d1 = __builtin_amdgcn_mfma_f32_16x16x32_bf16(a1, b, zero, 0, 0, 0);
#pragma unroll
    for (int j = 0; j < 4; ++j) {
      rmin0[j] = fminf(rmin0[j], d0[j]);
      rmin1[j] = fminf(rmin1[j], d1[j]);
    }
  }
  unsigned int* mywave = &rml[w * 33];
#pragma unroll
  for (int j = 0; j < 4; ++j) {
    atomicMin(&mywave[rid[j]],      encf(rmin0[j]));
    atomicMin(&mywave[16 + rid[j]], encf(rmin1[j]));
  }
  __syncthreads();
  if (tid < 32) {
    unsigned int mn = 0xFFFFFFFFu;
#pragma unroll
    for (int ww = 0; ww < 4; ++ww) mn = min(mn, rml[ww * 33 + tid]);
    atomicMin(&rowmin_u[row0 + tid], mn);
  }
}

// ---------------- Kernel 3: gate (1 block x 1024, verbatim) ------------------
__global__ __launch_bounds__(1024) void gate_kernel(
    const unsigned int* __restrict__ rowmin_u, const float* __restrict__ t2arr,
    const unsigned int* __restrict__ c2max_u,
    unsigned int* __restrict__ candcount, int* __restrict__ candlist) {
  __shared__ float sT[1024];
  __shared__ unsigned int cnt;
  int tid = threadIdx.x;
  float c2m = __uint_as_float(c2max_u[0]);
  float Tl = 3.4e38f;
  for (int i = tid; i < NMASK; i += 1024) {
    float a = decf(rowmin_u[i]);
    float e = fmaf(EPS_C, sqrtf(t2arr[i] * c2m), EPS_ABS);
    Tl = fminf(Tl, a + e);                          // NaN -> ignored
  }
  sT[tid] = Tl;
  if (tid == 0) cnt = 0u;
  __syncthreads();
  for (int st = 512; st > 0; st >>= 1) {
    if (tid < st) sT[tid] = fminf(sT[tid], sT[tid + st]);
    __syncthreads();
  }
  float T = sT[0];
  for (int i = tid; i < NMASK; i += 1024) {
    float a = decf(rowmin_u[i]);
    float e = fmaf(EPS_C, sqrtf(t2arr[i] * c2m), EPS_ABS);
    if (!(a - e > T)) {                             // NaN-safe: NaN -> candidate
      unsigned int pos = atomicAdd(&cnt, 1u);
      candlist[pos] = i;
    }
  }
  __syncthreads();
  if (tid == 0) candcount[0] = cnt;                 // plain store
}

// ---------------- Kernel 4: cproj — exact f32 -2t for candidates -------------
__global__ __launch_bounds__(256) void cproj_kernel(
    const float* __restrict__ x, const float* __restrict__ W,
    const int* __restrict__ origrow, const unsigned int* __restrict__ candcount,
    const int* __restrict__ candlist, float* __restrict__ tgtm) {
  int tid = threadIdx.x, bid = (int)blockIdx.x;
  int nc = (int)candcount[0];
  int ch = tid & 7;
  for (int idx = bid * 32 + (tid >> 3); idx < nc; idx += (int)gridDim.x * 32) {
    int row = origrow[candlist[idx]];
    float pd[16];
    proj_row8(x, W, row, ch, pd);                   // bit-identical to project
    if (ch == 0) {
      float* op = tgtm + (long)idx * 16;
#pragma unroll
      for (int c = 0; c < 16; ++c) op[c] = -2.0f * pd[c];
    }
  }
}

// ---------------- Kernel 5: rescore + rank-converting emit (verbatim) --------
__global__ __launch_bounds__(256) void rescore_kernel(
    const float* __restrict__ cbk, const float* __restrict__ c2,
    const float* __restrict__ tgtm, const float* __restrict__ t2arr,
    const int* __restrict__ origrow, const int* __restrict__ mask,
    const unsigned int* __restrict__ candcount, const int* __restrict__ candlist,
    unsigned long long* __restrict__ key, unsigned int* __restrict__ resctr,
    int* __restrict__ out) {
  __shared__ unsigned long long red[256];
  __shared__ int lastf;
  __shared__ unsigned int vlow_s;
  int tid = threadIdx.x, bid = (int)blockIdx.x;
  int nwork = (int)candcount[0] * 8;                // 8 octants x 1024 codes
  for (int wk = bid; wk < nwork; wk += (int)gridDim.x) {
    int ci = wk >> 3, oct = wk & 7;
    int r = candlist[ci];                           // slot, uniform per block
    float t2 = t2arr[r];
    int row = origrow[r];
    float tm[16];
    const float4* tp = (const float4*)(tgtm + (long)ci * 16);
#pragma unroll
    for (int q = 0; q < 4; ++q) {                   // uniform -> scalar loads
      float4 v = tp[q];
      tm[q*4+0] = v.x; tm[q*4+1] = v.y; tm[q*4+2] = v.z; tm[q*4+3] = v.w;
    }
    float minv = 3.4e38f; int mink = 0;
#pragma unroll 2
    for (int k = 0; k < 4; ++k) {                   // 4 codes/thread
      int code = oct * 1024 + k * 256 + tid;
      const float4* cp = (const float4*)(cbk + (long)code * CDIM);
      float4 c0 = cp[0], c1 = cp[1], c2v4 = cp[2], c3 = cp[3];
      float acc = fmaf(tm[0],  c0.x, c2[code]);
      acc = fmaf(tm[1],  c0.y, acc);   acc = fmaf(tm[2],  c0.z, acc);
      acc = fmaf(tm[3],  c0.w, acc);   acc = fmaf(tm[4],  c1.x, acc);
      acc = fmaf(tm[5],  c1.y, acc);   acc = fmaf(tm[6],  c1.z, acc);
      acc = fmaf(tm[7],  c1.w, acc);   acc = fmaf(tm[8],  c2v4.x, acc);
      acc = fmaf(tm[9],  c2v4.y, acc); acc = fmaf(tm[10], c2v4.z, acc);
      acc = fmaf(tm[11], c2v4.w, acc); acc = fmaf(tm[12], c3.x, acc);
      acc = fmaf(tm[13], c3.y, acc);   acc = fmaf(tm[14], c3.z, acc);
      acc = fmaf(tm[15], c3.w, acc);
      if (acc < minv) { minv = acc; mink = code; }
    }
    // tie-break on row*8192+code == lexicographic (row, code) == rank order
    red[tid] = ((unsigned long long)encf(t2 + minv) << 32)
        | (unsigned long long)((unsigned int)row * (unsigned int)NCODES + (unsigned int)mink);
    __syncthreads();
    for (int s = 128; s > 0; s >>= 1) {
      if (tid < s) { if (red[tid + s] < red[tid]) red[tid] = red[tid + s]; }
      __syncthreads();
    }
    if (tid == 0) atomicMin(key, red[0]);
    __syncthreads();                                // LDS reuse across wk
  }
  if (tid == 0) {
    __threadfence();
    lastf = (atomicAdd(resctr, 1u) == (unsigned int)gridDim.x - 1u) ? 1 : 0;
  }
  __syncthreads();
  if (lastf) {                                      // last block: rank + emit
    if (tid == 0)
      vlow_s = (unsigned int)(atomicMin(key, 0xFFFFFFFFFFFFFFFFull) & 0xFFFFFFFFull);
    __syncthreads();
    unsigned int vlow = vlow_s;
    int wrow = (int)(vlow >> 13), wcode = (int)(vlow & 8191u);
    int lo = tid * (NROWS / 256);
    int hi = lo + (NROWS / 256); if (hi > wrow) hi = wrow;
    int cnt = 0;
#pragma unroll 4
    for (int i = lo; i < hi; ++i) cnt += (mask[i] != 0);
    __shared__ int ps[256];
    ps[tid] = cnt;
    __syncthreads();
    for (int s = 128; s > 0; s >>= 1) {
      if (tid < s) ps[tid] += ps[tid + s];
      __syncthreads();
    }
    if (tid == 0) out[0] = ps[0] * NCODES + wcode;  // rank*8192 + code
  }
}

extern "C" void kernel_launch(void* const* d_in, const int* in_sizes, int n_in,
                              void* d_out, int out_size, void* d_ws, size_t ws_size,
                              hipStream_t stream) {
  const float* x    = (const float*)d_in[0];
  const int*   mask = (const int*)d_in[1];
  const float* W    = (const float*)d_in[2];
  const float* cbk  = (const float*)d_in[3];
  int* out = (int*)d_out;

  char* ws = (char*)d_ws;                                   // total 1,810,432 B (R6-proven)
  unsigned int*       resctr    = (unsigned int*)(ws + 4096);       // 4  (0-init)
  unsigned int*       slotctr   = (unsigned int*)(ws + 4100);       // 4  (0-init)
  unsigned int*       c2max_u   = (unsigned int*)(ws + 4104);       // 4  (0-init)
  unsigned int*       candcount = (unsigned int*)(ws + 4112);       // 4  (gate stores)
  unsigned long long* key       = (unsigned long long*)(ws + 8184); // 8  (0xFF-init)
  unsigned int*       rowmin_u  = (unsigned int*)(ws + 8192);       // 64 KiB (0xFF-init)
  float*              t2arr     = (float*)(ws + 73728);             // 64 KiB
  int*                origrow   = (int*)(ws + 139264);              // 64 KiB
  float*              c2        = (float*)(ws + 204800);            // 32 KiB
  unsigned short*     cbf32     = (unsigned short*)(ws + 237568);   // 512 KiB
  int*                candlist  = (int*)(ws + 237568);              // aliases cbf32 (dead by gate)
  unsigned short*     tbf32     = (unsigned short*)(ws + 761856);   // 1 MiB
  float*              tgtm      = (float*)(ws + 761856);            // aliases tbf32 (dead after phase1)

  hipMemsetAsync(ws + 4096, 0, 16, stream);                 // resctr, slotctr, c2max
  hipMemsetAsync(ws + 8184, 0xFF, 8 + 65536, stream);       // key + rowmin_u
  project_kernel<<<1024, 256, 0, stream>>>(x, mask, W, cbk, c2, cbf32, tbf32,
                                           t2arr, origrow, c2max_u, slotctr);
  phase1_kernel<<<2048, 256, 0, stream>>>(tbf32, cbf32, rowmin_u);
  gate_kernel<<<1, 1024, 0, stream>>>(rowmin_u, t2arr, c2max_u, candcount, candlist);
  cproj_kernel<<<512, 256, 0, stream>>>(x, W, origrow, candcount, candlist, tgtm);
  rescore_kernel<<<512, 256, 0, stream>>>(cbk, c2, tgtm, t2arr, origrow, mask,
                                          candcount, candlist, key, resctr, out);
}

// Round 13
// 100.822 us; speedup vs baseline: 1.4671x; 1.4671x over previous
//
#include <hip/hip_runtime.h>
#include <hip/hip_bf16.h>

// RandomProjectionQuantizer — MFMA screen, atomic-decongested project (R13).
//  x:(16,2048,320) f32, mask:(16,2048) i32 (exactly 16384 ones),
//  W:(16,320) f32, codebook:(8192,16) f32 -> scalar int32 label
//
//  R13 vs R12: removed both single-address atomic hot streams from project
//  (8192-lane atomicMax -> gate-side reduction; per-wave slot atomicAdd ->
//  per-block, 1024 total). memsets -> 1-block init kernel; rowmin_u init
//  folded into project. Projection math bit-identical to R12 (proven).

#define NMASK   16384
#define NROWS   32768
#define D       320
#define CDIM    16
#define NCODES  8192
#define EPS_C   0.0117f      // 1.5 * 2^-7  (bf16 RNE dot-error coefficient)
#define EPS_ABS 0.02f

typedef __attribute__((ext_vector_type(8))) short short8;
typedef __attribute__((ext_vector_type(4))) float f32x4;

__device__ inline unsigned int encf(float f) {
  unsigned int u = __float_as_uint(f);
  return (u & 0x80000000u) ? ~u : (u | 0x80000000u);
}
__device__ inline float decf(unsigned int u) {
  unsigned int b = (u & 0x80000000u) ? (u & 0x7fffffffu) : ~u;
  return __uint_as_float(b);
}
__device__ inline unsigned short f2bf(float f) {   // RNE f32->bf16
  unsigned int u = __float_as_uint(f);
  unsigned int r = u + 0x7fffu + ((u >> 16) & 1u);
  return (unsigned short)(r >> 16);
}
__device__ inline float bf2f(unsigned short h) {
  return __uint_as_float(((unsigned int)h) << 16);
}

// projection (R12 chunking): lane ch covers d in { j*32 + ch*4 .. +4 }.
// butterfly combine (xor 1,2,4). Bit-identical between project (LDS W) and
// cproj (global W).
__device__ inline void proj_row8(const float* __restrict__ x,
                                 const float* __restrict__ W,
                                 int row, int ch, float pd[16]) {
#pragma unroll
  for (int c = 0; c < 16; ++c) pd[c] = 0.f;
  const float* xr = x + (size_t)row * D + ch * 4;
  float4 xv[10];
#pragma unroll
  for (int j = 0; j < 10; ++j) xv[j] = *(const float4*)(xr + j * 32);
#pragma unroll
  for (int j = 0; j < 10; ++j) {
#pragma unroll
    for (int c = 0; c < 16; ++c) {
      const float4 wv = *(const float4*)(W + c * D + j * 32 + ch * 4);
      float acc = fmaf(xv[j].x, wv.x, pd[c]);
      acc = fmaf(xv[j].y, wv.y, acc);
      acc = fmaf(xv[j].z, wv.z, acc);
      pd[c] = fmaf(xv[j].w, wv.w, acc);
    }
  }
#pragma unroll
  for (int c = 0; c < 16; ++c) {
    pd[c] += __shfl_xor(pd[c], 1);
    pd[c] += __shfl_xor(pd[c], 2);
    pd[c] += __shfl_xor(pd[c], 4);
  }
}

// ---------------- Kernel 0: init (1 block x 64) ------------------------------
__global__ void init_kernel(unsigned int* __restrict__ ctrs,
                            unsigned long long* __restrict__ key) {
  if (threadIdx.x < 4) ctrs[threadIdx.x] = 0u;      // resctr, slotctr, spare x2
  if (threadIdx.x == 4) key[0] = 0xFFFFFFFFFFFFFFFFull;
}

// ---------------- Kernel 1: project (1024 blocks x 256) ----------------------
__global__ __launch_bounds__(256) void project_kernel(
    const float* __restrict__ x, const int* __restrict__ mask,
    const float* __restrict__ W, const float* __restrict__ cbk,
    float* __restrict__ c2, unsigned short* __restrict__ cbf32,
    unsigned short* __restrict__ tbf32, float* __restrict__ t2arr,
    int* __restrict__ origrow, unsigned int* __restrict__ rowmin_u,
    unsigned int* __restrict__ slotctr) {
  __shared__ float Wl[CDIM * D];                    // 20 KiB, natural layout
  __shared__ unsigned long long mb;
  __shared__ unsigned int wcnt[4], wbase[4];
  int tid = threadIdx.x, bid = (int)blockIdx.x;
  int chunk = bid >> 1, half = bid & 1;
  for (int i = tid; i < (CDIM * D) / 4; i += 256)
    ((float4*)Wl)[i] = ((const float4*)W)[i];
  if (tid < 64) {
    int m = mask[chunk * 64 + tid];
    unsigned long long bal = __ballot(m != 0);
    if (tid == 0) mb = bal;
  }
  if (tid < 16) rowmin_u[bid * 16 + tid] = 0xFFFFFFFFu;  // 1024 x 16 = 16384
  __syncthreads();

  if (bid < 512 && tid < 16) {                      // fused codes job (R5 fold)
    int k = bid * 16 + tid;
    const float4* p = (const float4*)(cbk + (long)k * CDIM);
    float s = 0.f; unsigned short nb[16];
#pragma unroll
    for (int q = 0; q < 4; ++q) {
      float4 v = p[q];
      s = fmaf(v.x, v.x, s); s = fmaf(v.y, v.y, s);
      s = fmaf(v.z, v.z, s); s = fmaf(v.w, v.w, s);
      nb[q*4+0] = f2bf(-2.0f * v.x); nb[q*4+1] = f2bf(-2.0f * v.y);
      nb[q*4+2] = f2bf(-2.0f * v.z); nb[q*4+3] = f2bf(-2.0f * v.w);
    }
    c2[k] = s;                                      // NO global atomicMax (R13)
    unsigned short g1 = f2bf(s);
    unsigned short g2 = f2bf(s - bf2f(g1));
    uint4 pk0, pk1, pk2, pk3;
    pk0.x = (unsigned int)nb[0]  | ((unsigned int)nb[1]  << 16);
    pk0.y = (unsigned int)nb[2]  | ((unsigned int)nb[3]  << 16);
    pk0.z = (unsigned int)nb[4]  | ((unsigned int)nb[5]  << 16);
    pk0.w = (unsigned int)nb[6]  | ((unsigned int)nb[7]  << 16);
    pk1.x = (unsigned int)nb[8]  | ((unsigned int)nb[9]  << 16);
    pk1.y = (unsigned int)nb[10] | ((unsigned int)nb[11] << 16);
    pk1.z = (unsigned int)nb[12] | ((unsigned int)nb[13] << 16);
    pk1.w = (unsigned int)nb[14] | ((unsigned int)nb[15] << 16);
    pk2.x = (unsigned int)g1 | ((unsigned int)g2 << 16); // dims 16,17: g1,g2
    pk2.y = 0x3F803F80u;                                 // dims 18,19: 1,1
    pk2.z = 0u; pk2.w = 0u;
    pk3.x = 0u; pk3.y = 0u; pk3.z = 0u; pk3.w = 0u;
    uint4* dst = (uint4*)(cbf32 + (long)k * 32);
    dst[0] = pk0; dst[1] = pk1; dst[2] = pk2; dst[3] = pk3;
  }

  unsigned long long B0 = mb;
  int r = tid >> 3, ch = tid & 7, lane = tid & 63, w = tid >> 6;
  int p = half * 32 + r;                            // bit position in chunk
  int row = chunk * 64 + p;
  int m = (int)((B0 >> p) & 1ull);

  // per-BLOCK slot assignment: one atomicAdd per block (R13)
  unsigned long long wbal = __ballot(m && ch == 0);
  if (lane == 0) wcnt[w] = (unsigned int)__popcll(wbal);
  __syncthreads();
  if (tid == 0) {
    unsigned int tot = wcnt[0] + wcnt[1] + wcnt[2] + wcnt[3];
    unsigned int b = tot ? atomicAdd(slotctr, tot) : 0u;
    wbase[0] = b;
    wbase[1] = b + wcnt[0];
    wbase[2] = b + wcnt[0] + wcnt[1];
    wbase[3] = b + wcnt[0] + wcnt[1] + wcnt[2];
  }
  __syncthreads();
  if (!m) return;                                   // no barriers past here

  // projection from LDS-W (R12-proven: coalesced x, conflict-free banks)
  const float* xr = x + (size_t)row * D + ch * 4;
  float4 xv[10];
#pragma unroll
  for (int j = 0; j < 10; ++j) xv[j] = *(const float4*)(xr + j * 32);
  float pd[16];
#pragma unroll
  for (int c = 0; c < 16; ++c) pd[c] = 0.f;
#pragma unroll
  for (int j = 0; j < 10; ++j) {
#pragma unroll
    for (int c = 0; c < 16; ++c) {
      const float4 wv = *(const float4*)&Wl[c * D + j * 32 + ch * 4];
      float acc = fmaf(xv[j].x, wv.x, pd[c]);
      acc = fmaf(xv[j].y, wv.y, acc);
      acc = fmaf(xv[j].z, wv.z, acc);
      pd[c] = fmaf(xv[j].w, wv.w, acc);
    }
  }
#pragma unroll
  for (int c = 0; c < 16; ++c) {
    pd[c] += __shfl_xor(pd[c], 1);
    pd[c] += __shfl_xor(pd[c], 2);
    pd[c] += __shfl_xor(pd[c], 4);
  }

  if (ch == 0) {
    int slot = (int)wbase[w] + __popcll(wbal & ((1ull << lane) - 1ull));
    float t2 = 0.f;
#pragma unroll
    for (int c = 0; c < 16; ++c) t2 = fmaf(pd[c], pd[c], t2);
    t2arr[slot] = t2;
    origrow[slot] = row;
    unsigned short tb[16];
#pragma unroll
    for (int c = 0; c < 16; ++c) tb[c] = f2bf(pd[c]);
    unsigned short h1 = f2bf(t2);
    unsigned short h2 = f2bf(t2 - bf2f(h1));
    uint4 pk0, pk1, pk2, pk3;
    pk0.x = (unsigned int)tb[0]  | ((unsigned int)tb[1]  << 16);
    pk0.y = (unsigned int)tb[2]  | ((unsigned int)tb[3]  << 16);
    pk0.z = (unsigned int)tb[4]  | ((unsigned int)tb[5]  << 16);
    pk0.w = (unsigned int)tb[6]  | ((unsigned int)tb[7]  << 16);
    pk1.x = (unsigned int)tb[8]  | ((unsigned int)tb[9]  << 16);
    pk1.y = (unsigned int)tb[10] | ((unsigned int)tb[11] << 16);
    pk1.z = (unsigned int)tb[12] | ((unsigned int)tb[13] << 16);
    pk1.w = (unsigned int)tb[14] | ((unsigned int)tb[15] << 16);
    pk2.x = 0x3F803F80u;                                 // dims 16,17: 1,1
    pk2.y = (unsigned int)h1 | ((unsigned int)h2 << 16); // dims 18,19: h1,h2
    pk2.z = 0u; pk2.w = 0u;
    pk3.x = 0u; pk3.y = 0u; pk3.z = 0u; pk3.w = 0u;
    uint4* dst = (uint4*)(tbf32 + (long)slot * 32);
    dst[0] = pk0; dst[1] = pk1; dst[2] = pk2; dst[3] = pk3;
  }
}

// ---------------- Kernel 2: calibrated per-row MFMA screening (verbatim) -----
__global__ __launch_bounds__(256) void phase1_kernel(
    const unsigned short* __restrict__ tbf32,
    const unsigned short* __restrict__ cbf32,
    unsigned int* __restrict__ rowmin_u) {
  __shared__ unsigned int rml[4 * 33];
  int tid = threadIdx.x;
  int w = tid >> 6, l = tid & 63, lr = l & 15, g = l >> 4;
  int strip = (int)blockIdx.x >> 2;                 // 0..511
  int seg   = ((int)blockIdx.x & 3) * 4 + w;        // 0..15
  int row0 = strip * 32;

  for (int i = tid; i < 4 * 33; i += 256) rml[i] = 0xFFFFFFFFu;
  __syncthreads();

  const f32x4 zero = {0.f, 0.f, 0.f, 0.f};
  short8 calA = {0,0,0,0,0,0,0,0}, calB = {0,0,0,0,0,0,0,0};
  if (g == 0) {
    calA[0] = (short)f2bf((float)(lr + 1));
    calB[0] = (short)0x3F80;                        // bf16 1.0
  }
  f32x4 cal = __builtin_amdgcn_mfma_f32_16x16x32_bf16(calA, calB, zero, 0, 0, 0);
  int rid[4];
#pragma unroll
  for (int j = 0; j < 4; ++j) {
    int v = (int)(cal[j] + 0.5f) - 1;
    rid[j] = v < 0 ? 0 : (v > 15 ? 15 : v);
  }

  const short8 a0 = *(const short8*)(tbf32 + (long)(row0 + lr) * 32 + g * 8);
  const short8 a1 = *(const short8*)(tbf32 + (long)(row0 + 16 + lr) * 32 + g * 8);
  f32x4 rmin0 = {3.4e38f, 3.4e38f, 3.4e38f, 3.4e38f};
  f32x4 rmin1 = rmin0;
  int code0 = seg * 512;
#pragma unroll 2
  for (int t = 0; t < 32; ++t) {
    int code = code0 + t * 16 + lr;
    short8 b = *(const short8*)(cbf32 + (long)code * 32 + g * 8);
    f32x4 d0 = __builtin_amdgcn_mfma_f32_16x16x32_bf16(a0, b, zero, 0, 0, 0);
    f32x4 d1 = __builtin_amdgcn_mfma_f32_16x16x32_bf16(a1, b, zero, 0, 0, 0);
#pragma unroll
    for (int j = 0; j < 4; ++j) {
      rmin0[j] = fminf(rmin0[j], d0[j]);
      rmin1[j] = fminf(rmin1[j], d1[j]);
    }
  }
  unsigned int* mywave = &rml[w * 33];
#pragma unroll
  for (int j = 0; j < 4; ++j) {
    atomicMin(&mywave[rid[j]],      encf(rmin0[j]));
    atomicMin(&mywave[16 + rid[j]], encf(rmin1[j]));
  }
  __syncthreads();
  if (tid < 32) {
    unsigned int mn = 0xFFFFFFFFu;
#pragma unroll
    for (int ww = 0; ww < 4; ++ww) mn = min(mn, rml[ww * 33 + tid]);
    atomicMin(&rowmin_u[row0 + tid], mn);
  }
}

// ---------------- Kernel 3: gate (1 block x 1024) ----------------------------
__global__ __launch_bounds__(1024) void gate_kernel(
    const unsigned int* __restrict__ rowmin_u, const float* __restrict__ t2arr,
    const float* __restrict__ c2,
    unsigned int* __restrict__ candcount, int* __restrict__ candlist) {
  __shared__ float sT[1024];
  __shared__ float c2m_s;
  __shared__ unsigned int cnt;
  int tid = threadIdx.x;
  float cm = 0.f;                                   // c2 >= 0
#pragma unroll
  for (int i = 0; i < 8; ++i) cm = fmaxf(cm, c2[tid + i * 1024]);
  sT[tid] = cm;
  if (tid == 0) cnt = 0u;
  __syncthreads();
  for (int st = 512; st > 0; st >>= 1) {
    if (tid < st) sT[tid] = fmaxf(sT[tid], sT[tid + st]);
    __syncthreads();
  }
  if (tid == 0) c2m_s = sT[0];
  __syncthreads();
  float c2m = c2m_s;
  float Tl = 3.4e38f;
  for (int i = tid; i < NMASK; i += 1024) {
    float a = decf(rowmin_u[i]);
    float e = fmaf(EPS_C, sqrtf(t2arr[i] * c2m), EPS_ABS);
    Tl = fminf(Tl, a + e);                          // NaN -> ignored
  }
  sT[tid] = Tl;
  __syncthreads();
  for (int st = 512; st > 0; st >>= 1) {
    if (tid < st) sT[tid] = fminf(sT[tid], sT[tid + st]);
    __syncthreads();
  }
  float T = sT[0];
  for (int i = tid; i < NMASK; i += 1024) {
    float a = decf(rowmin_u[i]);
    float e = fmaf(EPS_C, sqrtf(t2arr[i] * c2m), EPS_ABS);
    if (!(a - e > T)) {                             // NaN-safe: NaN -> candidate
      unsigned int pos = atomicAdd(&cnt, 1u);
      candlist[pos] = i;
    }
  }
  __syncthreads();
  if (tid == 0) candcount[0] = cnt;                 // plain store
}

// ---------------- Kernel 4: cproj — exact f32 -2t for candidates (verbatim) --
__global__ __launch_bounds__(256) void cproj_kernel(
    const float* __restrict__ x, const float* __restrict__ W,
    const int* __restrict__ origrow, const unsigned int* __restrict__ candcount,
    const int* __restrict__ candlist, float* __restrict__ tgtm) {
  int tid = threadIdx.x, bid = (int)blockIdx.x;
  int nc = (int)candcount[0];
  int ch = tid & 7;
  for (int idx = bid * 32 + (tid >> 3); idx < nc; idx += (int)gridDim.x * 32) {
    int row = origrow[candlist[idx]];
    float pd[16];
    proj_row8(x, W, row, ch, pd);                   // bit-identical to project
    if (ch == 0) {
      float* op = tgtm + (long)idx * 16;
#pragma unroll
      for (int c = 0; c < 16; ++c) op[c] = -2.0f * pd[c];
    }
  }
}

// ---------------- Kernel 5: rescore + rank-converting emit (verbatim) --------
__global__ __launch_bounds__(256) void rescore_kernel(
    const float* __restrict__ cbk, const float* __restrict__ c2,
    const float* __restrict__ tgtm, const float* __restrict__ t2arr,
    const int* __restrict__ origrow, const int* __restrict__ mask,
    const unsigned int* __restrict__ candcount, const int* __restrict__ candlist,
    unsigned long long* __restrict__ key, unsigned int* __restrict__ resctr,
    int* __restrict__ out) {
  __shared__ unsigned long long red[256];
  __shared__ int lastf;
  __shared__ unsigned int vlow_s;
  int tid = threadIdx.x, bid = (int)blockIdx.x;
  int nwork = (int)candcount[0] * 8;                // 8 octants x 1024 codes
  for (int wk = bid; wk < nwork; wk += (int)gridDim.x) {
    int ci = wk >> 3, oct = wk & 7;
    int r = candlist[ci];                           // slot, uniform per block
    float t2 = t2arr[r];
    int row = origrow[r];
    float tm[16];
    const float4* tp = (const float4*)(tgtm + (long)ci * 16);
#pragma unroll
    for (int q = 0; q < 4; ++q) {                   // uniform -> scalar loads
      float4 v = tp[q];
      tm[q*4+0] = v.x; tm[q*4+1] = v.y; tm[q*4+2] = v.z; tm[q*4+3] = v.w;
    }
    float minv = 3.4e38f; int mink = 0;
#pragma unroll 2
    for (int k = 0; k < 4; ++k) {                   // 4 codes/thread
      int code = oct * 1024 + k * 256 + tid;
      const float4* cp = (const float4*)(cbk + (long)code * CDIM);
      float4 c0 = cp[0], c1 = cp[1], c2v4 = cp[2], c3 = cp[3];
      float acc = fmaf(tm[0],  c0.x, c2[code]);
      acc = fmaf(tm[1],  c0.y, acc);   acc = fmaf(tm[2],  c0.z, acc);
      acc = fmaf(tm[3],  c0.w, acc);   acc = fmaf(tm[4],  c1.x, acc);
      acc = fmaf(tm[5],  c1.y, acc);   acc = fmaf(tm[6],  c1.z, acc);
      acc = fmaf(tm[7],  c1.w, acc);   acc = fmaf(tm[8],  c2v4.x, acc);
      acc = fmaf(tm[9],  c2v4.y, acc); acc = fmaf(tm[10], c2v4.z, acc);
      acc = fmaf(tm[11], c2v4.w, acc); acc = fmaf(tm[12], c3.x, acc);
      acc = fmaf(tm[13], c3.y, acc);   acc = fmaf(tm[14], c3.z, acc);
      acc = fmaf(tm[15], c3.w, acc);
      if (acc < minv) { minv = acc; mink = code; }
    }
    // tie-break on row*8192+code == lexicographic (row, code) == rank order
    red[tid] = ((unsigned long long)encf(t2 + minv) << 32)
        | (unsigned long long)((unsigned int)row * (unsigned int)NCODES + (unsigned int)mink);
    __syncthreads();
    for (int s = 128; s > 0; s >>= 1) {
      if (tid < s) { if (red[tid + s] < red[tid]) red[tid] = red[tid + s]; }
      __syncthreads();
    }
    if (tid == 0) atomicMin(key, red[0]);
    __syncthreads();                                // LDS reuse across wk
  }
  if (tid == 0) {
    __threadfence();
    lastf = (atomicAdd(resctr, 1u) == (unsigned int)gridDim.x - 1u) ? 1 : 0;
  }
  __syncthreads();
  if (lastf) {                                      // last block: rank + emit
    if (tid == 0)
      vlow_s = (unsigned int)(atomicMin(key, 0xFFFFFFFFFFFFFFFFull) & 0xFFFFFFFFull);
    __syncthreads();
    unsigned int vlow = vlow_s;
    int wrow = (int)(vlow >> 13), wcode = (int)(vlow & 8191u);
    int lo = tid * (NROWS / 256);
    int hi = lo + (NROWS / 256); if (hi > wrow) hi = wrow;
    int cnt = 0;
#pragma unroll 4
    for (int i = lo; i < hi; ++i) cnt += (mask[i] != 0);
    __shared__ int ps[256];
    ps[tid] = cnt;
    __syncthreads();
    for (int s = 128; s > 0; s >>= 1) {
      if (tid < s) ps[tid] += ps[tid + s];
      __syncthreads();
    }
    if (tid == 0) out[0] = ps[0] * NCODES + wcode;  // rank*8192 + code
  }
}

extern "C" void kernel_launch(void* const* d_in, const int* in_sizes, int n_in,
                              void* d_out, int out_size, void* d_ws, size_t ws_size,
                              hipStream_t stream) {
  const float* x    = (const float*)d_in[0];
  const int*   mask = (const int*)d_in[1];
  const float* W    = (const float*)d_in[2];
  const float* cbk  = (const float*)d_in[3];
  int* out = (int*)d_out;

  char* ws = (char*)d_ws;                                   // total 1,810,432 B (R6-proven)
  unsigned int*       ctrs      = (unsigned int*)(ws + 4096);       // resctr, slotctr, +2 spare
  unsigned int*       resctr    = (unsigned int*)(ws + 4096);
  unsigned int*       slotctr   = (unsigned int*)(ws + 4100);
  unsigned int*       candcount = (unsigned int*)(ws + 4112);       // gate stores
  unsigned long long* key       = (unsigned long long*)(ws + 8184); // init kernel
  unsigned int*       rowmin_u  = (unsigned int*)(ws + 8192);       // 64 KiB (project inits)
  float*              t2arr     = (float*)(ws + 73728);             // 64 KiB
  int*                origrow   = (int*)(ws + 139264);              // 64 KiB
  float*              c2        = (float*)(ws + 204800);            // 32 KiB
  unsigned short*     cbf32     = (unsigned short*)(ws + 237568);   // 512 KiB
  int*                candlist  = (int*)(ws + 237568);              // aliases cbf32 (dead by gate)
  unsigned short*     tbf32     = (unsigned short*)(ws + 761856);   // 1 MiB
  float*              tgtm      = (float*)(ws + 761856);            // aliases tbf32 (dead after phase1)

  init_kernel<<<1, 64, 0, stream>>>(ctrs, key);
  project_kernel<<<1024, 256, 0, stream>>>(x, mask, W, cbk, c2, cbf32, tbf32,
                                           t2arr, origrow, rowmin_u, slotctr);
  phase1_kernel<<<2048, 256, 0, stream>>>(tbf32, cbf32, rowmin_u);
  gate_kernel<<<1, 1024, 0, stream>>>(rowmin_u, t2arr, c2, candcount, candlist);
  cproj_kernel<<<512, 256, 0, stream>>>(x, W, origrow, candcount, candlist, tgtm);
  rescore_kernel<<<512, 256, 0, stream>>>(cbk, c2, tgtm, t2arr, origrow, mask,
                                          candcount, candlist, key, resctr, out);
}

// Round 14
// 89.365 us; speedup vs baseline: 1.6552x; 1.1282x over previous
//
#include <hip/hip_runtime.h>
#include <hip/hip_bf16.h>

// RandomProjectionQuantizer — MFMA screen; cproj de-spilled via LDS-W (R14).
//  x:(16,2048,320) f32, mask:(16,2048) i32 (exactly 16384 ones),
//  W:(16,320) f32, codebook:(8192,16) f32 -> scalar int32 label
//
//  R14 vs R13: cproj (67.6us, VGPR=256 spill, occ 0.002%) now stages W in LDS
//  exactly like project (VGPR~60 proven) — global-W unrolled loads were being
//  register-batched by the scheduler into a 256-VGPR spill. Same FMA chain,
//  same values -> bit-identical t. Everything else R13-verbatim.

#define NMASK   16384
#define NROWS   32768
#define D       320
#define CDIM    16
#define NCODES  8192
#define EPS_C   0.0117f      // 1.5 * 2^-7  (bf16 RNE dot-error coefficient)
#define EPS_ABS 0.02f

typedef __attribute__((ext_vector_type(8))) short short8;
typedef __attribute__((ext_vector_type(4))) float f32x4;

__device__ inline unsigned int encf(float f) {
  unsigned int u = __float_as_uint(f);
  return (u & 0x80000000u) ? ~u : (u | 0x80000000u);
}
__device__ inline float decf(unsigned int u) {
  unsigned int b = (u & 0x80000000u) ? (u & 0x7fffffffu) : ~u;
  return __uint_as_float(b);
}
__device__ inline unsigned short f2bf(float f) {   // RNE f32->bf16
  unsigned int u = __float_as_uint(f);
  unsigned int r = u + 0x7fffu + ((u >> 16) & 1u);
  return (unsigned short)(r >> 16);
}
__device__ inline float bf2f(unsigned short h) {
  return __uint_as_float(((unsigned int)h) << 16);
}

// shared LDS-W projection body (project + cproj): lane ch covers d in
// { j*32 + ch*4 .. +4 }, x prefetched, butterfly combine (xor 1,2,4).
__device__ inline void proj_lds(const float* __restrict__ x,
                                const float* __restrict__ Wl,
                                int row, int ch, float pd[16]) {
  const float* xr = x + (size_t)row * D + ch * 4;
  float4 xv[10];
#pragma unroll
  for (int j = 0; j < 10; ++j) xv[j] = *(const float4*)(xr + j * 32);
#pragma unroll
  for (int c = 0; c < 16; ++c) pd[c] = 0.f;
#pragma unroll
  for (int j = 0; j < 10; ++j) {
#pragma unroll
    for (int c = 0; c < 16; ++c) {
      const float4 wv = *(const float4*)&Wl[c * D + j * 32 + ch * 4];
      float acc = fmaf(xv[j].x, wv.x, pd[c]);
      acc = fmaf(xv[j].y, wv.y, acc);
      acc = fmaf(xv[j].z, wv.z, acc);
      pd[c] = fmaf(xv[j].w, wv.w, acc);
    }
  }
#pragma unroll
  for (int c = 0; c < 16; ++c) {
    pd[c] += __shfl_xor(pd[c], 1);
    pd[c] += __shfl_xor(pd[c], 2);
    pd[c] += __shfl_xor(pd[c], 4);
  }
}

// ---------------- Kernel 0: init (1 block x 64) ------------------------------
__global__ void init_kernel(unsigned int* __restrict__ ctrs,
                            unsigned long long* __restrict__ key) {
  if (threadIdx.x < 4) ctrs[threadIdx.x] = 0u;      // resctr, slotctr, spare x2
  if (threadIdx.x == 4) key[0] = 0xFFFFFFFFFFFFFFFFull;
}

// ---------------- Kernel 1: project (1024 blocks x 256) ----------------------
__global__ __launch_bounds__(256) void project_kernel(
    const float* __restrict__ x, const int* __restrict__ mask,
    const float* __restrict__ W, const float* __restrict__ cbk,
    float* __restrict__ c2, unsigned short* __restrict__ cbf32,
    unsigned short* __restrict__ tbf32, float* __restrict__ t2arr,
    int* __restrict__ origrow, unsigned int* __restrict__ rowmin_u,
    unsigned int* __restrict__ slotctr) {
  __shared__ float Wl[CDIM * D];                    // 20 KiB, natural layout
  __shared__ unsigned long long mb;
  __shared__ unsigned int wcnt[4], wbase[4];
  int tid = threadIdx.x, bid = (int)blockIdx.x;
  int chunk = bid >> 1, half = bid & 1;
  for (int i = tid; i < (CDIM * D) / 4; i += 256)
    ((float4*)Wl)[i] = ((const float4*)W)[i];
  if (tid < 64) {
    int m = mask[chunk * 64 + tid];
    unsigned long long bal = __ballot(m != 0);
    if (tid == 0) mb = bal;
  }
  if (tid < 16) rowmin_u[bid * 16 + tid] = 0xFFFFFFFFu;  // 1024 x 16 = 16384
  __syncthreads();

  if (bid < 512 && tid < 16) {                      // fused codes job (R5 fold)
    int k = bid * 16 + tid;
    const float4* p = (const float4*)(cbk + (long)k * CDIM);
    float s = 0.f; unsigned short nb[16];
#pragma unroll
    for (int q = 0; q < 4; ++q) {
      float4 v = p[q];
      s = fmaf(v.x, v.x, s); s = fmaf(v.y, v.y, s);
      s = fmaf(v.z, v.z, s); s = fmaf(v.w, v.w, s);
      nb[q*4+0] = f2bf(-2.0f * v.x); nb[q*4+1] = f2bf(-2.0f * v.y);
      nb[q*4+2] = f2bf(-2.0f * v.z); nb[q*4+3] = f2bf(-2.0f * v.w);
    }
    c2[k] = s;
    unsigned short g1 = f2bf(s);
    unsigned short g2 = f2bf(s - bf2f(g1));
    uint4 pk0, pk1, pk2, pk3;
    pk0.x = (unsigned int)nb[0]  | ((unsigned int)nb[1]  << 16);
    pk0.y = (unsigned int)nb[2]  | ((unsigned int)nb[3]  << 16);
    pk0.z = (unsigned int)nb[4]  | ((unsigned int)nb[5]  << 16);
    pk0.w = (unsigned int)nb[6]  | ((unsigned int)nb[7]  << 16);
    pk1.x = (unsigned int)nb[8]  | ((unsigned int)nb[9]  << 16);
    pk1.y = (unsigned int)nb[10] | ((unsigned int)nb[11] << 16);
    pk1.z = (unsigned int)nb[12] | ((unsigned int)nb[13] << 16);
    pk1.w = (unsigned int)nb[14] | ((unsigned int)nb[15] << 16);
    pk2.x = (unsigned int)g1 | ((unsigned int)g2 << 16); // dims 16,17: g1,g2
    pk2.y = 0x3F803F80u;                                 // dims 18,19: 1,1
    pk2.z = 0u; pk2.w = 0u;
    pk3.x = 0u; pk3.y = 0u; pk3.z = 0u; pk3.w = 0u;
    uint4* dst = (uint4*)(cbf32 + (long)k * 32);
    dst[0] = pk0; dst[1] = pk1; dst[2] = pk2; dst[3] = pk3;
  }

  unsigned long long B0 = mb;
  int r = tid >> 3, ch = tid & 7, lane = tid & 63, w = tid >> 6;
  int p = half * 32 + r;                            // bit position in chunk
  int row = chunk * 64 + p;
  int m = (int)((B0 >> p) & 1ull);

  // per-BLOCK slot assignment: one atomicAdd per block (R13-proven)
  unsigned long long wbal = __ballot(m && ch == 0);
  if (lane == 0) wcnt[w] = (unsigned int)__popcll(wbal);
  __syncthreads();
  if (tid == 0) {
    unsigned int tot = wcnt[0] + wcnt[1] + wcnt[2] + wcnt[3];
    unsigned int b = tot ? atomicAdd(slotctr, tot) : 0u;
    wbase[0] = b;
    wbase[1] = b + wcnt[0];
    wbase[2] = b + wcnt[0] + wcnt[1];
    wbase[3] = b + wcnt[0] + wcnt[1] + wcnt[2];
  }
  __syncthreads();
  if (!m) return;                                   // no barriers past here

  float pd[16];
  proj_lds(x, Wl, row, ch, pd);                     // R12-proven body

  if (ch == 0) {
    int slot = (int)wbase[w] + __popcll(wbal & ((1ull << lane) - 1ull));
    float t2 = 0.f;
#pragma unroll
    for (int c = 0; c < 16; ++c) t2 = fmaf(pd[c], pd[c], t2);
    t2arr[slot] = t2;
    origrow[slot] = row;
    unsigned short tb[16];
#pragma unroll
    for (int c = 0; c < 16; ++c) tb[c] = f2bf(pd[c]);
    unsigned short h1 = f2bf(t2);
    unsigned short h2 = f2bf(t2 - bf2f(h1));
    uint4 pk0, pk1, pk2, pk3;
    pk0.x = (unsigned int)tb[0]  | ((unsigned int)tb[1]  << 16);
    pk0.y = (unsigned int)tb[2]  | ((unsigned int)tb[3]  << 16);
    pk0.z = (unsigned int)tb[4]  | ((unsigned int)tb[5]  << 16);
    pk0.w = (unsigned int)tb[6]  | ((unsigned int)tb[7]  << 16);
    pk1.x = (unsigned int)tb[8]  | ((unsigned int)tb[9]  << 16);
    pk1.y = (unsigned int)tb[10] | ((unsigned int)tb[11] << 16);
    pk1.z = (unsigned int)tb[12] | ((unsigned int)tb[13] << 16);
    pk1.w = (unsigned int)tb[14] | ((unsigned int)tb[15] << 16);
    pk2.x = 0x3F803F80u;                                 // dims 16,17: 1,1
    pk2.y = (unsigned int)h1 | ((unsigned int)h2 << 16); // dims 18,19: h1,h2
    pk2.z = 0u; pk2.w = 0u;
    pk3.x = 0u; pk3.y = 0u; pk3.z = 0u; pk3.w = 0u;
    uint4* dst = (uint4*)(tbf32 + (long)slot * 32);
    dst[0] = pk0; dst[1] = pk1; dst[2] = pk2; dst[3] = pk3;
  }
}

// ---------------- Kernel 2: calibrated per-row MFMA screening (verbatim) -----
__global__ __launch_bounds__(256) void phase1_kernel(
    const unsigned short* __restrict__ tbf32,
    const unsigned short* __restrict__ cbf32,
    unsigned int* __restrict__ rowmin_u) {
  __shared__ unsigned int rml[4 * 33];
  int tid = threadIdx.x;
  int w = tid >> 6, l = tid & 63, lr = l & 15, g = l >> 4;
  int strip = (int)blockIdx.x >> 2;                 // 0..511
  int seg   = ((int)blockIdx.x & 3) * 4 + w;        // 0..15
  int row0 = strip * 32;

  for (int i = tid; i < 4 * 33; i += 256) rml[i] = 0xFFFFFFFFu;
  __syncthreads();

  const f32x4 zero = {0.f, 0.f, 0.f, 0.f};
  short8 calA = {0,0,0,0,0,0,0,0}, calB = {0,0,0,0,0,0,0,0};
  if (g == 0) {
    calA[0] = (short)f2bf((float)(lr + 1));
    calB[0] = (short)0x3F80;                        // bf16 1.0
  }
  f32x4 cal = __builtin_amdgcn_mfma_f32_16x16x32_bf16(calA, calB, zero, 0, 0, 0);
  int rid[4];
#pragma unroll
  for (int j = 0; j < 4; ++j) {
    int v = (int)(cal[j] + 0.5f) - 1;
    rid[j] = v < 0 ? 0 : (v > 15 ? 15 : v);
  }

  const short8 a0 = *(const short8*)(tbf32 + (long)(row0 + lr) * 32 + g * 8);
  const short8 a1 = *(const short8*)(tbf32 + (long)(row0 + 16 + lr) * 32 + g * 8);
  f32x4 rmin0 = {3.4e38f, 3.4e38f, 3.4e38f, 3.4e38f};
  f32x4 rmin1 = rmin0;
  int code0 = seg * 512;
#pragma unroll 2
  for (int t = 0; t < 32; ++t) {
    int code = code0 + t * 16 + lr;
    short8 b = *(const short8*)(cbf32 + (long)code * 32 + g * 8);
    f32x4 d0 = __builtin_amdgcn_mfma_f32_16x16x32_bf16(a0, b, zero, 0, 0, 0);
    f32x4 d1 = __builtin_amdgcn_mfma_f32_16x16x32_bf16(a1, b, zero, 0, 0, 0);
#pragma unroll
    for (int j = 0; j < 4; ++j) {
      rmin0[j] = fminf(rmin0[j], d0[j]);
      rmin1[j] = fminf(rmin1[j], d1[j]);
    }
  }
  unsigned int* mywave = &rml[w * 33];
#pragma unroll
  for (int j = 0; j < 4; ++j) {
    atomicMin(&mywave[rid[j]],      encf(rmin0[j]));
    atomicMin(&mywave[16 + rid[j]], encf(rmin1[j]));
  }
  __syncthreads();
  if (tid < 32) {
    unsigned int mn = 0xFFFFFFFFu;
#pragma unroll
    for (int ww = 0; ww < 4; ++ww) mn = min(mn, rml[ww * 33 + tid]);
    atomicMin(&rowmin_u[row0 + tid], mn);
  }
}

// ---------------- Kernel 3: gate (1 block x 1024, verbatim) ------------------
__global__ __launch_bounds__(1024) void gate_kernel(
    const unsigned int* __restrict__ rowmin_u, const float* __restrict__ t2arr,
    const float* __restrict__ c2,
    unsigned int* __restrict__ candcount, int* __restrict__ candlist) {
  __shared__ float sT[1024];
  __shared__ float c2m_s;
  __shared__ unsigned int cnt;
  int tid = threadIdx.x;
  float cm = 0.f;                                   // c2 >= 0
#pragma unroll
  for (int i = 0; i < 8; ++i) cm = fmaxf(cm, c2[tid + i * 1024]);
  sT[tid] = cm;
  if (tid == 0) cnt = 0u;
  __syncthreads();
  for (int st = 512; st > 0; st >>= 1) {
    if (tid < st) sT[tid] = fmaxf(sT[tid], sT[tid + st]);
    __syncthreads();
  }
  if (tid == 0) c2m_s = sT[0];
  __syncthreads();
  float c2m = c2m_s;
  float Tl = 3.4e38f;
  for (int i = tid; i < NMASK; i += 1024) {
    float a = decf(rowmin_u[i]);
    float e = fmaf(EPS_C, sqrtf(t2arr[i] * c2m), EPS_ABS);
    Tl = fminf(Tl, a + e);                          // NaN -> ignored
  }
  sT[tid] = Tl;
  __syncthreads();
  for (int st = 512; st > 0; st >>= 1) {
    if (tid < st) sT[tid] = fminf(sT[tid], sT[tid + st]);
    __syncthreads();
  }
  float T = sT[0];
  for (int i = tid; i < NMASK; i += 1024) {
    float a = decf(rowmin_u[i]);
    float e = fmaf(EPS_C, sqrtf(t2arr[i] * c2m), EPS_ABS);
    if (!(a - e > T)) {                             // NaN-safe: NaN -> candidate
      unsigned int pos = atomicAdd(&cnt, 1u);
      candlist[pos] = i;
    }
  }
  __syncthreads();
  if (tid == 0) candcount[0] = cnt;                 // plain store
}

// ---------------- Kernel 4: cproj — LDS-W exact f32 -2t for candidates -------
// One candidate per 8-lane group, no outer loop; blocks with no candidates
// exit before staging. Same chain as project -> bit-identical t.
__global__ __launch_bounds__(256) void cproj_kernel(
    const float* __restrict__ x, const float* __restrict__ W,
    const int* __restrict__ origrow, const unsigned int* __restrict__ candcount,
    const int* __restrict__ candlist, float* __restrict__ tgtm) {
  int tid = threadIdx.x, bid = (int)blockIdx.x;
  int nc = (int)candcount[0];
  if (bid * 32 >= nc) return;                       // whole block idle
  __shared__ float Wl[CDIM * D];                    // 20 KiB
  for (int i = tid; i < (CDIM * D) / 4; i += 256)
    ((float4*)Wl)[i] = ((const float4*)W)[i];
  __syncthreads();
  int idx = bid * 32 + (tid >> 3);                  // candidate index
  int ch  = tid & 7;
  if (idx >= nc) return;
  int row = origrow[candlist[idx]];
  float pd[16];
  proj_lds(x, Wl, row, ch, pd);                     // bit-identical to project
  if (ch == 0) {
    float* op = tgtm + (long)idx * 16;
#pragma unroll
    for (int c = 0; c < 16; ++c) op[c] = -2.0f * pd[c];
  }
}

// ---------------- Kernel 5: rescore + rank-converting emit (verbatim) --------
__global__ __launch_bounds__(256) void rescore_kernel(
    const float* __restrict__ cbk, const float* __restrict__ c2,
    const float* __restrict__ tgtm, const float* __restrict__ t2arr,
    const int* __restrict__ origrow, const int* __restrict__ mask,
    const unsigned int* __restrict__ candcount, const int* __restrict__ candlist,
    unsigned long long* __restrict__ key, unsigned int* __restrict__ resctr,
    int* __restrict__ out) {
  __shared__ unsigned long long red[256];
  __shared__ int lastf;
  __shared__ unsigned int vlow_s;
  int tid = threadIdx.x, bid = (int)blockIdx.x;
  int nwork = (int)candcount[0] * 8;                // 8 octants x 1024 codes
  for (int wk = bid; wk < nwork; wk += (int)gridDim.x) {
    int ci = wk >> 3, oct = wk & 7;
    int r = candlist[ci];                           // slot, uniform per block
    float t2 = t2arr[r];
    int row = origrow[r];
    float tm[16];
    const float4* tp = (const float4*)(tgtm + (long)ci * 16);
#pragma unroll
    for (int q = 0; q < 4; ++q) {                   // uniform -> scalar loads
      float4 v = tp[q];
      tm[q*4+0] = v.x; tm[q*4+1] = v.y; tm[q*4+2] = v.z; tm[q*4+3] = v.w;
    }
    float minv = 3.4e38f; int mink = 0;
#pragma unroll 2
    for (int k = 0; k < 4; ++k) {                   // 4 codes/thread
      int code = oct * 1024 + k * 256 + tid;
      const float4* cp = (const float4*)(cbk + (long)code * CDIM);
      float4 c0 = cp[0], c1 = cp[1], c2v4 = cp[2], c3 = cp[3];
      float acc = fmaf(tm[0],  c0.x, c2[code]);
      acc = fmaf(tm[1],  c0.y, acc);   acc = fmaf(tm[2],  c0.z, acc);
      acc = fmaf(tm[3],  c0.w, acc);   acc = fmaf(tm[4],  c1.x, acc);
      acc = fmaf(tm[5],  c1.y, acc);   acc = fmaf(tm[6],  c1.z, acc);
      acc = fmaf(tm[7],  c1.w, acc);   acc = fmaf(tm[8],  c2v4.x, acc);
      acc = fmaf(tm[9],  c2v4.y, acc); acc = fmaf(tm[10], c2v4.z, acc);
      acc = fmaf(tm[11], c2v4.w, acc); acc = fmaf(tm[12], c3.x, acc);
      acc = fmaf(tm[13], c3.y, acc);   acc = fmaf(tm[14], c3.z, acc);
      acc = fmaf(tm[15], c3.w, acc);
      if (acc < minv) { minv = acc; mink = code; }
    }
    // tie-break on row*8192+code == lexicographic (row, code) == rank order
    red[tid] = ((unsigned long long)encf(t2 + minv) << 32)
        | (unsigned long long)((unsigned int)row * (unsigned int)NCODES + (unsigned int)mink);
    __syncthreads();
    for (int s = 128; s > 0; s >>= 1) {
      if (tid < s) { if (red[tid + s] < red[tid]) red[tid] = red[tid + s]; }
      __syncthreads();
    }
    if (tid == 0) atomicMin(key, red[0]);
    __syncthreads();                                // LDS reuse across wk
  }
  if (tid == 0) {
    __threadfence();
    lastf = (atomicAdd(resctr, 1u) == (unsigned int)gridDim.x - 1u) ? 1 : 0;
  }
  __syncthreads();
  if (lastf) {                                      // last block: rank + emit
    if (tid == 0)
      vlow_s = (unsigned int)(atomicMin(key, 0xFFFFFFFFFFFFFFFFull) & 0xFFFFFFFFull);
    __syncthreads();
    unsigned int vlow = vlow_s;
    int wrow = (int)(vlow >> 13), wcode = (int)(vlow & 8191u);
    int lo = tid * (NROWS / 256);
    int hi = lo + (NROWS / 256); if (hi > wrow) hi = wrow;
    int cnt = 0;
#pragma unroll 4
    for (int i = lo; i < hi; ++i) cnt += (mask[i] != 0);
    __shared__ int ps[256];
    ps[tid] = cnt;
    __syncthreads();
    for (int s = 128; s > 0; s >>= 1) {
      if (tid < s) ps[tid] += ps[tid + s];
      __syncthreads();
    }
    if (tid == 0) out[0] = ps[0] * NCODES + wcode;  // rank*8192 + code
  }
}

extern "C" void kernel_launch(void* const* d_in, const int* in_sizes, int n_in,
                              void* d_out, int out_size, void* d_ws, size_t ws_size,
                              hipStream_t stream) {
  const float* x    = (const float*)d_in[0];
  const int*   mask = (const int*)d_in[1];
  const float* W    = (const float*)d_in[2];
  const float* cbk  = (const float*)d_in[3];
  int* out = (int*)d_out;

  char* ws = (char*)d_ws;                                   // total 1,810,432 B (R6-proven)
  unsigned int*       ctrs      = (unsigned int*)(ws + 4096);       // resctr, slotctr, +2 spare
  unsigned int*       resctr    = (unsigned int*)(ws + 4096);
  unsigned int*       slotctr   = (unsigned int*)(ws + 4100);
  unsigned int*       candcount = (unsigned int*)(ws + 4112);       // gate stores
  unsigned long long* key       = (unsigned long long*)(ws + 8184); // init kernel
  unsigned int*       rowmin_u  = (unsigned int*)(ws + 8192);       // 64 KiB (project inits)
  float*              t2arr     = (float*)(ws + 73728);             // 64 KiB
  int*                origrow   = (int*)(ws + 139264);              // 64 KiB
  float*              c2        = (float*)(ws + 204800);            // 32 KiB
  unsigned short*     cbf32     = (unsigned short*)(ws + 237568);   // 512 KiB
  int*                candlist  = (int*)(ws + 237568);              // aliases cbf32 (dead by gate)
  unsigned short*     tbf32     = (unsigned short*)(ws + 761856);   // 1 MiB
  float*              tgtm      = (float*)(ws + 761856);            // aliases tbf32 (dead after phase1)

  init_kernel<<<1, 64, 0, stream>>>(ctrs, key);
  project_kernel<<<1024, 256, 0, stream>>>(x, mask, W, cbk, c2, cbf32, tbf32,
                                           t2arr, origrow, rowmin_u, slotctr);
  phase1_kernel<<<2048, 256, 0, stream>>>(tbf32, cbf32, rowmin_u);
  gate_kernel<<<1, 1024, 0, stream>>>(rowmin_u, t2arr, c2, candcount, candlist);
  cproj_kernel<<<512, 256, 0, stream>>>(x, W, origrow, candcount, candlist, tgtm);
  rescore_kernel<<<512, 256, 0, stream>>>(cbk, c2, tgtm, t2arr, origrow, mask,
                                          candcount, candlist, key, resctr, out);
}